// Round 11
// baseline (298.018 us; speedup 1.0000x reference)
//
#include <hip/hip_runtime.h>
#include <hip/hip_bf16.h>

// MultiHeadSelfAttention  B=1, S=4096, D=1024, H=16, HD=64. fp32 I/O.
// bf16 MFMA 16x16x32; global_load_lds staging; zero-shift exact softmax.
// R11: grid 512 -> 1024 for attn (single variable). R10 pinned occupancy at
//     ~18% (2 blocks/CU ceiling 25%); VGPR=112 and LDS=33KB admit 4
//     blocks/CU (16 waves/CU, ceiling 50%). Per-XCD queues + stealing
//     (R10, verified: FETCH back to 12.9MB) unchanged; 256 surplus blocks
//     drain-probe and exit. GEMM = R8 swizzle (verified).

#define S_LEN 4096
#define D_DIM 1024
#define NHEAD 16
#define HDIM  64

typedef __hip_bfloat16 bf16;
typedef __attribute__((ext_vector_type(8))) short bf16x8v;
typedef __attribute__((ext_vector_type(4))) float f32x4;
typedef __attribute__((ext_vector_type(2))) unsigned int u32x2;

#define MFMA16(a, b, c) __builtin_amdgcn_mfma_f32_16x16x32_bf16((a), (b), (c), 0, 0, 0)

#if __has_builtin(__builtin_amdgcn_exp2f)
#define EXP2F(x) __builtin_amdgcn_exp2f(x)
#else
#define EXP2F(x) exp2f(x)
#endif

// log2(e) folded into the Q-projection scale: softmax(exp2(s*log2e)) == softmax(exp(s))
#define QSCALE (0.125f * 1.4426950408889634f)

template<int N> struct IC { static constexpr int value = N; };

// Async global->LDS DMA, 16 B per lane (m97 contract: LDS = uniform base + lane*16).
__device__ __forceinline__ void async_cp16(const void* g, void* l) {
    __builtin_amdgcn_global_load_lds(
        (const __attribute__((address_space(1))) unsigned int*)g,
        (__attribute__((address_space(3))) unsigned int*)l, 16, 0, 0);
}

// pack two f32 -> one u32 of 2x bf16 (lo in [15:0], hi in [31:16]), RNE
__device__ __forceinline__ unsigned int cvtpk_bf16(float lo, float hi) {
    unsigned int r;
    asm("v_cvt_pk_bf16_f32 %0, %1, %2" : "=v"(r) : "v"(lo), "v"(hi));
    return r;
}

// Hardware XCD id, 0..7 on MI355X (wave-uniform). If this ever misreads,
// work stealing still drains every queue -> correctness unaffected.
__device__ __forceinline__ int xcc_id() {
    int x;
    asm volatile("s_getreg_b32 %0, hwreg(HW_REG_XCC_ID)" : "=s"(x));
    return x & 7;
}

// ---------------------------------------------------------------------------
// fp32 -> bf16 elementwise, 3 tensors fused via blockIdx.z.
// ---------------------------------------------------------------------------
__global__ __launch_bounds__(256) void cvt_bf16_k(
    const float* __restrict__ x0, const float* __restrict__ x1,
    const float* __restrict__ x2,
    bf16* __restrict__ y0, bf16* __restrict__ y1, bf16* __restrict__ y2)
{
    const float* x = (blockIdx.z == 0) ? x0 : (blockIdx.z == 1) ? x1 : x2;
    bf16*       y = (blockIdx.z == 0) ? y0 : (blockIdx.z == 1) ? y1 : y2;
    const size_t i = ((size_t)blockIdx.x * 256 + threadIdx.x);
    const float4 v = ((const float4*)x)[i];
    union { bf16 h[4]; short4 s; } u;
    u.h[0] = __float2bfloat16(v.x);
    u.h[1] = __float2bfloat16(v.y);
    u.h[2] = __float2bfloat16(v.z);
    u.h[3] = __float2bfloat16(v.w);
    ((short4*)y)[i] = u.s;
}

// ---------------------------------------------------------------------------
// Wt[n][k] = bf16(W[k][n]), 4 weight matrices fused via blockIdx.z.
// Also zeroes the 8 per-XCD job-queue counters (runs first in the stream,
// so counters reset inside the graph on every replay).
// ---------------------------------------------------------------------------
__global__ __launch_bounds__(256) void transpose_cvt_k(
    const float* __restrict__ W0, const float* __restrict__ W1,
    const float* __restrict__ W2, const float* __restrict__ W3,
    bf16* __restrict__ T0, bf16* __restrict__ T1,
    bf16* __restrict__ T2, bf16* __restrict__ T3,
    int* jq)
{
    if (jq && blockIdx.x == 0 && blockIdx.y == 0 && blockIdx.z == 0 &&
        threadIdx.x < 8)
        jq[threadIdx.x << 5] = 0;
    const float* W = (blockIdx.z == 0) ? W0 : (blockIdx.z == 1) ? W1
                   : (blockIdx.z == 2) ? W2 : W3;
    bf16*       Wt = (blockIdx.z == 0) ? T0 : (blockIdx.z == 1) ? T1
                   : (blockIdx.z == 2) ? T2 : T3;
    __shared__ float t[32][33];
    const int bx = blockIdx.x << 5, by = blockIdx.y << 5;
    const int tx = threadIdx.x & 31, ty = threadIdx.x >> 5;
#pragma unroll
    for (int i = 0; i < 32; i += 8)
        t[ty + i][tx] = W[(size_t)(by + ty + i) * D_DIM + bx + tx];
    __syncthreads();
#pragma unroll
    for (int i = 0; i < 32; i += 8)
        Wt[(size_t)(bx + ty + i) * D_DIM + by + tx] = __float2bfloat16(t[tx][ty + i]);
}

// ---------------------------------------------------------------------------
// GEMM: C(4096x1024) = A @ Wt^T + bias, then *scale.
// Tile BM=128, BN=64, BK=64; 4 waves 2x2. global_load_lds width-16 staging.
// XCD-locality remap + double-buffered staging (R6) + XOR swizzle (R8,
// verified: bank-conflicts gone, gemm left top-5).
// mode 0: bf16 head-major; mode 2: bf16 [h][hd][row]; mode 1: fp32 row-major.
// ---------------------------------------------------------------------------
struct GemmJob {
    const bf16* A; const bf16* Wt; const float* bias; void* out;
    int mode; float scale;
};

__global__ __launch_bounds__(256) void gemm_k(GemmJob j0, GemmJob j1, GemmJob j2)
{
    const GemmJob j = (blockIdx.z == 0) ? j0 : (blockIdx.z == 1) ? j1 : j2;
    const int K = D_DIM;

    // XCD-locality remap (bijective: nb = gx*gy = 512, divisible by 8).
    const int nx  = gridDim.x;
    const int lin = blockIdx.y * nx + blockIdx.x;
    const int per = (nx * gridDim.y) >> 3;
    const int bmn = (lin & 7) * per + (lin >> 3);
    const int bn = (bmn % nx) << 6;
    const int bm = (bmn / nx) << 7;

    const int tid = threadIdx.x;
    const int w = tid >> 6, lane = tid & 63;
    const int col = lane & 15, g = lane >> 4;
    const int wr = (w >> 1) << 6, wc = (w & 1) << 5;
    const int c7 = col & 7;

    __shared__ bf16 As[2][128 * 64];
    __shared__ bf16 Bs[2][64 * 64];

    f32x4 acc[4][2];
#pragma unroll
    for (int i = 0; i < 4; ++i)
#pragma unroll
        for (int jj = 0; jj < 2; ++jj) acc[i][jj] = (f32x4){0.f, 0.f, 0.f, 0.f};

    auto stage = [&](int buf, int kb) {
#pragma unroll
        for (int e = 0; e < 4; ++e) {
            const int l2 = (e << 8) + tid;
            const int row = l2 >> 3, kc = l2 & 7;
            async_cp16(j.A + (size_t)(bm + row) * K + kb + ((kc ^ (row & 7)) << 3),
                       &As[buf][l2 << 3]);
        }
#pragma unroll
        for (int e = 0; e < 2; ++e) {
            const int l2 = (e << 8) + tid;
            const int row = l2 >> 3, kc = l2 & 7;
            async_cp16(j.Wt + (size_t)(bn + row) * K + kb + ((kc ^ (row & 7)) << 3),
                       &Bs[buf][l2 << 3]);
        }
    };

    stage(0, 0);
    __syncthreads();                       // buf0 ready
    int cur = 0;

    for (int kb = 0; kb < K; kb += 64) {
        if (kb + 64 < K) stage(cur ^ 1, kb + 64);   // prefetch during compute

#pragma unroll
        for (int s = 0; s < 2; ++s) {
            const int gsw = (((s << 2) + g) ^ c7) << 3;   // swizzled granule
            bf16x8v af[4], bfv[2];
#pragma unroll
            for (int i = 0; i < 4; ++i)
                af[i] = *(const bf16x8v*)&As[cur][((wr + (i << 4) + col) << 6) + gsw];
#pragma unroll
            for (int jj = 0; jj < 2; ++jj)
                bfv[jj] = *(const bf16x8v*)&Bs[cur][((wc + (jj << 4) + col) << 6) + gsw];
#pragma unroll
            for (int i = 0; i < 4; ++i)
#pragma unroll
                for (int jj = 0; jj < 2; ++jj)
                    acc[i][jj] = MFMA16(af[i], bfv[jj], acc[i][jj]);
        }

        __syncthreads();                   // drains prefetch + buffer reuse
        cur ^= 1;
    }

#pragma unroll
    for (int i = 0; i < 4; ++i)
#pragma unroll
    for (int jj = 0; jj < 2; ++jj)
#pragma unroll
    for (int reg = 0; reg < 4; ++reg) {
        const int row = bm + wr + (i << 4) + (g << 2) + reg;
        const int cg  = bn + wc + (jj << 4) + col;
        const float vv = (acc[i][jj][reg] + j.bias[cg]) * j.scale;
        if (j.mode == 0)
            ((bf16*)j.out)[(((size_t)(cg >> 6)) * S_LEN + row) * HDIM + (cg & 63)] =
                __float2bfloat16(vv);
        else if (j.mode == 2)
            ((bf16*)j.out)[((size_t)(cg >> 6) * HDIM + (cg & 63)) * S_LEN + row] =
                __float2bfloat16(vv);
        else
            ((float*)j.out)[(size_t)row * D_DIM + cg] = vv;
    }
}

// ---------------------------------------------------------------------------
// Flash attention, zero-shift softmax, swapped QK^T, 2 q-groups/wave, split-k.
// Block = 128 q-rows (4 waves x 32: groups A (+0) and B (+64) share every
// K/V LDS fragment). Qp pre-scaled by log2e/8.
//
// Job system (mode 1): 8 per-XCD queues, 96 jobs each, covering heads
// {2x, 2x+1} for queue x (K/V working set 2 MB <= 4 MB XCD L2). Heavy-first
// local index jl in [0,96):
//   jl<32:  h=2x+(jl&1), qb=16+(jl>>1): tiles [2qb-30,2qb+2),
//           split chunk 1, diagonal (32 tiles)
//   jl>=32, jj=jl-32, s=jj>>2, r=(jj>>1)&1, h=2x+(jj&1):
//     r==0: qb=31-s: tiles [0,2qb-30), split chunk 0      (32-2s tiles)
//     r==1: qb=15-s: tiles [0,2qb+2),  unsplit, diagonal  (32-2s tiles)
// Blocks pop their own XCD's queue (HW_REG_XCC_ID), then steal round-robin
// from the other 7 -> every job executes exactly once under ANY block->XCD
// mapping. End-of-job barrier closes inter-job LDS reuse.
// mode 0: static, bid-derived (fallback path).
//
// Diagonal peeling (compile-time MODE): main-loop tiles mask-free;
// tile 2qb   = MODE 1 (A diag-masked, B full);
// tile 2qb+1 = MODE 2 (A skipped entirely — P_A == 0 there; B diag-masked).
// Split partials additive (zero-shift): Opart/lpart layout == R4 (verified),
// combine_k does (O0+O1)/(l0+l1) for q-rows 2048..4095.
// ---------------------------------------------------------------------------
__global__ __launch_bounds__(256) void attn_mfma_k(
    const bf16* __restrict__ Qp, const bf16* __restrict__ Kp,
    const bf16* __restrict__ Vt, bf16* __restrict__ ctx,
    float* __restrict__ Opart, float* __restrict__ lpart,
    int* __restrict__ jq, int mode)
{
    __shared__ bf16 Ks[2][4096];     // [buf][t(2b)][G(3b)][c(4b)][8]
    __shared__ bf16 Vs[2][4096];
    __shared__ int jbox;

    const int tid = threadIdx.x, w = tid >> 6, lane = tid & 63;
    const int col = lane & 15, g = lane >> 4;
    const int x0 = (mode == 1) ? xcc_id() : 0;

    for (int qi = 0; qi < 8; ++qi) {
        const int x = (x0 + qi) & 7;
        for (;;) {
            int h, qb, t0, nt, chunk;
            bool dosplit, hdiag;
            if (mode == 1) {
                if (tid == 0) jbox = atomicAdd(&jq[x << 5], 1);
                __syncthreads();               // publish jbox
                const int jl = jbox;
                if (jl >= 96) break;           // queue drained -> try next
                if (jl < 32) {
                    h = (x << 1) + (jl & 1); qb = 16 + (jl >> 1);
                    t0 = 2 * qb - 30; nt = 32; dosplit = true; chunk = 1; hdiag = true;
                } else {
                    const int jj = jl - 32;
                    const int s = jj >> 2, r = (jj >> 1) & 1;
                    h = (x << 1) + (jj & 1);
                    if (r == 0) { qb = 31 - s; t0 = 0; nt = 2 * qb - 30; dosplit = true;  chunk = 0; hdiag = false; }
                    else        { qb = 15 - s; t0 = 0; nt = 2 * qb + 2;  dosplit = false; chunk = 0; hdiag = true;  }
                }
            } else {
                const int bid = blockIdx.x;
                h = bid & 15; qb = 31 - (bid >> 4);
                t0 = 0; nt = 2 * qb + 2; dosplit = false; chunk = 0; hdiag = true;
            }

            const int q0 = qb << 7;
            const bf16* Kh = Kp + (size_t)h * S_LEN * HDIM;
            const bf16* Vh = Vt + (size_t)h * HDIM * S_LEN;

            const int qrowA = q0 + (w << 4) + col;
            const int qrowB = qrowA + 64;
            const size_t qbaseA = ((size_t)h * S_LEN + qrowA) * HDIM + (g << 3);
            const size_t qbaseB = qbaseA + (size_t)64 * HDIM;
            const bf16x8v qfA0 = *(const bf16x8v*)(Qp + qbaseA);
            const bf16x8v qfA1 = *(const bf16x8v*)(Qp + qbaseA + 32);
            const bf16x8v qfB0 = *(const bf16x8v*)(Qp + qbaseB);
            const bf16x8v qfB1 = *(const bf16x8v*)(Qp + qbaseB + 32);

            float plA = 0.f, plB = 0.f;
            f32x4 accA[4], accB[4];
#pragma unroll
            for (int t = 0; t < 4; ++t) {
                accA[t] = (f32x4){0.f, 0.f, 0.f, 0.f};
                accB[t] = (f32x4){0.f, 0.f, 0.f, 0.f};
            }

            auto stage = [&](int buf, int kb) {
                const int kk0 = kb << 6;
#pragma unroll
                for (int e = 0; e < 2; ++e) {
                    const int lin = (e << 8) + tid;            // granule 0..511
                    const int t = lin >> 7, G = (lin >> 4) & 7, c = lin & 15;
                    async_cp16(Kh + (size_t)(kk0 + (t << 4) + c) * HDIM + (G << 3),
                               &Ks[buf][lin << 3]);
                    async_cp16(Vh + (size_t)((t << 4) + c) * S_LEN + kk0 + (G << 3),
                               &Vs[buf][lin << 3]);
                }
            };

            // MODE 0: no masks.  MODE 1: A diag-masked, B full.  MODE 2: A
            // skipped, B diag-masked.
            auto body = [&](auto mtag, int kb, int cur) {
                constexpr int MODE = decltype(mtag)::value;
                const int kk0 = kb << 6;
                const bf16* Kc = Ks[cur];
                const bf16* Vc = Vs[cur];

                f32x4 saA[4], saB[4];
#pragma unroll
                for (int t = 0; t < 4; ++t) {
                    saA[t] = (f32x4){0.f, 0.f, 0.f, 0.f};
                    saB[t] = (f32x4){0.f, 0.f, 0.f, 0.f};
                }
                __builtin_amdgcn_s_setprio(1);
#pragma unroll
                for (int t = 0; t < 4; ++t) {
                    const bf16x8v kf0 = *(const bf16x8v*)&Kc[((t << 7) + (g << 4) + col) << 3];
                    const bf16x8v kf1 = *(const bf16x8v*)&Kc[((t << 7) + 64 + (g << 4) + col) << 3];
                    if (MODE != 2) {
                        saA[t] = MFMA16(kf0, qfA0, saA[t]);
                        saA[t] = MFMA16(kf1, qfA1, saA[t]);
                    }
                    saB[t] = MFMA16(kf0, qfB0, saB[t]);
                    saB[t] = MFMA16(kf1, qfB1, saB[t]);
                }
                __builtin_amdgcn_s_setprio(0);

#pragma unroll
                for (int t = 0; t < 4; ++t) {
#pragma unroll
                    for (int reg = 0; reg < 4; ++reg) {
                        const int kidx = kk0 + (t << 4) + (g << 2) + reg;
                        if (MODE != 2) {
                            float pA;
                            if (MODE == 1 && kidx > qrowA) pA = 0.f;
                            else                           pA = EXP2F(saA[t][reg]);
                            plA += pA; saA[t][reg] = pA;
                        }
                        float pB;
                        if (MODE == 2 && kidx > qrowB) pB = 0.f;
                        else                           pB = EXP2F(saB[t][reg]);
                        plB += pB; saB[t][reg] = pB;
                    }
                }

                union { unsigned int wd[4]; bf16x8v v; } pA0, pA1, pB0, pB1;
                if (MODE != 2) {
                    unsigned int c0[4], c1[4];
#pragma unroll
                    for (int t = 0; t < 4; ++t) {
                        c0[t] = cvtpk_bf16(saA[t][0], saA[t][1]);
                        c1[t] = cvtpk_bf16(saA[t][2], saA[t][3]);
                    }
                    u32x2 r0 = __builtin_amdgcn_permlane32_swap(c0[0], c0[1], false, false);
                    u32x2 r1 = __builtin_amdgcn_permlane32_swap(c1[0], c1[1], false, false);
                    u32x2 s0 = __builtin_amdgcn_permlane16_swap(r0[0], r0[1], false, false);
                    u32x2 s1 = __builtin_amdgcn_permlane16_swap(r1[0], r1[1], false, false);
                    pA0.wd[0] = s0[0]; pA0.wd[1] = s1[0]; pA0.wd[2] = s0[1]; pA0.wd[3] = s1[1];
                    r0 = __builtin_amdgcn_permlane32_swap(c0[2], c0[3], false, false);
                    r1 = __builtin_amdgcn_permlane32_swap(c1[2], c1[3], false, false);
                    s0 = __builtin_amdgcn_permlane16_swap(r0[0], r0[1], false, false);
                    s1 = __builtin_amdgcn_permlane16_swap(r1[0], r1[1], false, false);
                    pA1.wd[0] = s0[0]; pA1.wd[1] = s1[0]; pA1.wd[2] = s0[1]; pA1.wd[3] = s1[1];
                }
                {
                    unsigned int c0[4], c1[4];
#pragma unroll
                    for (int t = 0; t < 4; ++t) {
                        c0[t] = cvtpk_bf16(saB[t][0], saB[t][1]);
                        c1[t] = cvtpk_bf16(saB[t][2], saB[t][3]);
                    }
                    u32x2 r0 = __builtin_amdgcn_permlane32_swap(c0[0], c0[1], false, false);
                    u32x2 r1 = __builtin_amdgcn_permlane32_swap(c1[0], c1[1], false, false);
                    u32x2 s0 = __builtin_amdgcn_permlane16_swap(r0[0], r0[1], false, false);
                    u32x2 s1 = __builtin_amdgcn_permlane16_swap(r1[0], r1[1], false, false);
                    pB0.wd[0] = s0[0]; pB0.wd[1] = s1[0]; pB0.wd[2] = s0[1]; pB0.wd[3] = s1[1];
                    r0 = __builtin_amdgcn_permlane32_swap(c0[2], c0[3], false, false);
                    r1 = __builtin_amdgcn_permlane32_swap(c1[2], c1[3], false, false);
                    s0 = __builtin_amdgcn_permlane16_swap(r0[0], r0[1], false, false);
                    s1 = __builtin_amdgcn_permlane16_swap(r1[0], r1[1], false, false);
                    pB1.wd[0] = s0[0]; pB1.wd[1] = s1[0]; pB1.wd[2] = s0[1]; pB1.wd[3] = s1[1];
                }

                __builtin_amdgcn_s_setprio(1);
#pragma unroll
                for (int t = 0; t < 4; ++t) {
                    const bf16x8v vf0 = *(const bf16x8v*)&Vc[((t << 7) + (g << 4) + col) << 3];
                    const bf16x8v vf1 = *(const bf16x8v*)&Vc[((t << 7) + 64 + (g << 4) + col) << 3];
                    if (MODE != 2) {
                        accA[t] = MFMA16(vf0, pA0.v, accA[t]);
                        accA[t] = MFMA16(vf1, pA1.v, accA[t]);
                    }
                    accB[t] = MFMA16(vf0, pB0.v, accB[t]);
                    accB[t] = MFMA16(vf1, pB1.v, accB[t]);
                }
                __builtin_amdgcn_s_setprio(0);
            };

            int kb = t0, cur = 0;
            const int kend = t0 + nt;
            stage(0, kb);
            __syncthreads();                       // buf0 ready

            const int nmain = hdiag ? nt - 2 : nt;
            for (int i = 0; i < nmain; ++i, ++kb) {
                if (kb + 1 < kend) stage(cur ^ 1, kb + 1);
                body(IC<0>{}, kb, cur);
                __syncthreads();                   // drains prefetch + buffer reuse
                cur ^= 1;
            }
            if (hdiag) {
                stage(cur ^ 1, kb + 1);            // last tile prefetch
                body(IC<1>{}, kb, cur);            // tile 2qb: A diag, B full
                __syncthreads();
                cur ^= 1; ++kb;
                body(IC<2>{}, kb, cur);            // tile 2qb+1: A skipped, B diag
            }

            // row-sums: reduce across the 4 g-groups (lane bits 4,5); q = col
            float lA = plA, lB = plB;
            lA += __shfl_xor(lA, 16); lA += __shfl_xor(lA, 32);
            lB += __shfl_xor(lB, 16); lB += __shfl_xor(lB, 32);

            if (!dosplit) {
                const float invA = 1.f / lA;
                const float invB = 1.f / lB;
#pragma unroll
                for (int t = 0; t < 4; ++t) {
                    union { bf16 hh[4]; short4 s4; } uA, uB;
#pragma unroll
                    for (int reg = 0; reg < 4; ++reg) {
                        uA.hh[reg] = __float2bfloat16(accA[t][reg] * invA);
                        uB.hh[reg] = __float2bfloat16(accB[t][reg] * invB);
                    }
                    *(short4*)&ctx[(size_t)qrowA * D_DIM + h * HDIM + (t << 4) + (g << 2)] = uA.s4;
                    *(short4*)&ctx[(size_t)qrowB * D_DIM + h * HDIM + (t << 4) + (g << 2)] = uB.s4;
                }
            } else {
                // unnormalized f32 partials; additive across chunks (zero-shift)
                const int srowA = ((qb - 16) << 7) + (w << 4) + col;      // 0..2047
                const int srowB = srowA + 64;
                float* OpA = Opart + (((size_t)chunk * NHEAD + h) * 2048 + srowA) * HDIM;
                float* OpB = Opart + (((size_t)chunk * NHEAD + h) * 2048 + srowB) * HDIM;
#pragma unroll
                for (int t = 0; t < 4; ++t) {
                    *(f32x4*)&OpA[(t << 4) + (g << 2)] = accA[t];
                    *(f32x4*)&OpB[(t << 4) + (g << 2)] = accB[t];
                }
                if (g == 0) {
                    lpart[((size_t)chunk * NHEAD + h) * 2048 + srowA] = lA;
                    lpart[((size_t)chunk * NHEAD + h) * 2048 + srowB] = lB;
                }
            }

            __syncthreads();               // LDS safe before next job's stage
            if (mode != 1) return;         // static path: one job per block
        }
        if (mode != 1) return;
    }
}

// ---------------------------------------------------------------------------
// Combine split-k partials: ctx[2048+srow] = (O0+O1)/(l0+l1).
// 32768 (h,srow) rows x 64 d; 16 threads/row (4 d each), 16 rows/block.
// ---------------------------------------------------------------------------
__global__ __launch_bounds__(256) void combine_k(
    const float* __restrict__ Opart, const float* __restrict__ lpart,
    bf16* __restrict__ ctx)
{
    const int tid = threadIdx.x;
    const int row = (blockIdx.x << 4) + (tid >> 4);   // 0..32767 = h*2048+srow
    const int d4  = (tid & 15) << 2;
    const int h   = row >> 11;
    const int srow = row & 2047;
    const float4 a = *(const float4*)&Opart[(size_t)row * HDIM + d4];
    const float4 b = *(const float4*)&Opart[(size_t)(32768 + row) * HDIM + d4];
    const float inv = 1.f / (lpart[row] + lpart[32768 + row]);
    union { bf16 hh[4]; short4 s4; } u;
    u.hh[0] = __float2bfloat16((a.x + b.x) * inv);
    u.hh[1] = __float2bfloat16((a.y + b.y) * inv);
    u.hh[2] = __float2bfloat16((a.z + b.z) * inv);
    u.hh[3] = __float2bfloat16((a.w + b.w) * inv);
    const int qrow = 2048 + srow;
    *(short4*)&ctx[(size_t)qrow * D_DIM + h * HDIM + d4] = u.s4;
}

// ---------------------------------------------------------------------------
extern "C" void kernel_launch(void* const* d_in, const int* in_sizes, int n_in,
                              void* d_out, int out_size, void* d_ws, size_t ws_size,
                              hipStream_t stream)
{
    const float* q  = (const float*)d_in[0];
    const float* k  = (const float*)d_in[1];
    const float* v  = (const float*)d_in[2];
    // d_in[3] = causal mask, implemented analytically
    const float* Wq = (const float*)d_in[4];
    const float* bq = (const float*)d_in[5];
    const float* Wk = (const float*)d_in[6];
    const float* bk = (const float*)d_in[7];
    const float* Wv = (const float*)d_in[8];
    const float* bv = (const float*)d_in[9];
    const float* Wo = (const float*)d_in[10];
    const float* bo = (const float*)d_in[11];

    const size_t PE  = (size_t)S_LEN * D_DIM;
    const size_t WTE = (size_t)D_DIM * D_DIM;

    const dim3 tg(32, 32, 4);
    const dim3 gg(D_DIM / 64, S_LEN / 128, 1);
    const dim3 gg3(D_DIM / 64, S_LEN / 128, 3);
    const dim3 cg((unsigned)(PE / 1024), 1, 3);

    if (ws_size >= (size_t)64 * 1024 * 1024) {
        // ---- fused-QKV path (56 MB + partials + counters) ----
        bf16* Qb = (bf16*)d_ws;
        bf16* Kb = Qb + PE;
        bf16* Vb = Kb + PE;
        bf16* Qp = Vb + PE;
        bf16* Kp = Qp + PE;
        bf16* Vt = Kp + PE;
        bf16* Wtq = Vt + PE;
        bf16* Wtk = Wtq + WTE;
        bf16* Wtv = Wtk + WTE;
        bf16* Wto = Wtv + WTE;
        bf16* ctx = Qb;
        // Kb/Vb are dead after the projection GEMMs -> reuse for partials.
        float* Opart = (float*)Kb;                 // 2*16*2048*64 f32 = 16 MB
        float* lpart = (float*)(Wto + WTE);        // 2*16*2048 f32 = 256 KB
        int*   jq    = (int*)(lpart + 2 * NHEAD * 2048);   // 8 ctrs, stride 32

        transpose_cvt_k<<<tg, 256, 0, stream>>>(Wq, Wk, Wv, Wo, Wtq, Wtk, Wtv, Wto, jq);
        cvt_bf16_k<<<cg, 256, 0, stream>>>(q, k, v, Qb, Kb, Vb);

        GemmJob jqj{Qb, Wtq, bq, Qp, 0, QSCALE};
        GemmJob jkj{Kb, Wtk, bk, Kp, 0, 1.0f};
        GemmJob jvj{Vb, Wtv, bv, Vt, 2, 1.0f};
        gemm_k<<<gg3, 256, 0, stream>>>(jqj, jkj, jvj);

        attn_mfma_k<<<dim3(1024), 256, 0, stream>>>(Qp, Kp, Vt, ctx, Opart, lpart, jq, 1);
        combine_k<<<dim3(2048), 256, 0, stream>>>(Opart, lpart, ctx);

        GemmJob joj{ctx, Wto, bo, d_out, 1, 1.0f};
        gemm_k<<<gg, 256, 0, stream>>>(joj, joj, joj);
    } else {
        // ---- sequential path (40 MB, no split-k workspace) ----
        bf16* X  = (bf16*)d_ws;
        bf16* Qp = X + PE;
        bf16* Kp = Qp + PE;
        bf16* Vt = Kp + PE;
        bf16* Wtq = Vt + PE;
        bf16* Wtk = Wtq + WTE;
        bf16* Wtv = Wtk + WTE;
        bf16* Wto = Wtv + WTE;

        transpose_cvt_k<<<tg, 256, 0, stream>>>(Wq, Wk, Wv, Wo, Wtq, Wtk, Wtv, Wto, nullptr);

        const dim3 cg1((unsigned)(PE / 1024), 1, 1);
        cvt_bf16_k<<<cg1, 256, 0, stream>>>(q, q, q, X, X, X);
        GemmJob jqj{X, Wtq, bq, Qp, 0, QSCALE};
        gemm_k<<<gg, 256, 0, stream>>>(jqj, jqj, jqj);
        cvt_bf16_k<<<cg1, 256, 0, stream>>>(k, k, k, X, X, X);
        GemmJob jkj{X, Wtk, bk, Kp, 0, 1.0f};
        gemm_k<<<gg, 256, 0, stream>>>(jkj, jkj, jkj);
        cvt_bf16_k<<<cg1, 256, 0, stream>>>(v, v, v, X, X, X);
        GemmJob jvj{X, Wtv, bv, Vt, 2, 1.0f};
        gemm_k<<<gg, 256, 0, stream>>>(jvj, jvj, jvj);

        attn_mfma_k<<<dim3(512), 256, 0, stream>>>(Qp, Kp, Vt, X, nullptr, nullptr, nullptr, 0);

        GemmJob joj{X, Wto, bo, d_out, 1, 1.0f};
        gemm_k<<<gg, 256, 0, stream>>>(joj, joj, joj);
    }
}

// Round 12
// 292.536 us; speedup vs baseline: 1.0187x; 1.0187x over previous
//
#include <hip/hip_runtime.h>
#include <hip/hip_bf16.h>

// MultiHeadSelfAttention  B=1, S=4096, D=1024, H=16, HD=64. fp32 I/O.
// bf16 MFMA 16x16x32; global_load_lds staging; zero-shift exact softmax.
// R12: attn single-buffer K/V (LDS 33->16.4 KB). Occupancy tracks LDS/block
//     (16KB->38%, 33KB->18%, grid-invariant: R4 vs R10/R11) -> halving LDS
//     doubles residency; TLP hides the per-tile DMA drain (R1: dbuf worth
//     only ~1%). Static R6 job table, grid 768 (queue cost 5-8us vs static,
//     refuted R9-R11; machinery deleted). GEMM = R8 swizzle (verified).

#define S_LEN 4096
#define D_DIM 1024
#define NHEAD 16
#define HDIM  64

typedef __hip_bfloat16 bf16;
typedef __attribute__((ext_vector_type(8))) short bf16x8v;
typedef __attribute__((ext_vector_type(4))) float f32x4;
typedef __attribute__((ext_vector_type(2))) unsigned int u32x2;

#define MFMA16(a, b, c) __builtin_amdgcn_mfma_f32_16x16x32_bf16((a), (b), (c), 0, 0, 0)

#if __has_builtin(__builtin_amdgcn_exp2f)
#define EXP2F(x) __builtin_amdgcn_exp2f(x)
#else
#define EXP2F(x) exp2f(x)
#endif

// log2(e) folded into the Q-projection scale: softmax(exp2(s*log2e)) == softmax(exp(s))
#define QSCALE (0.125f * 1.4426950408889634f)

template<int N> struct IC { static constexpr int value = N; };

// Async global->LDS DMA, 16 B per lane (m97 contract: LDS = uniform base + lane*16).
__device__ __forceinline__ void async_cp16(const void* g, void* l) {
    __builtin_amdgcn_global_load_lds(
        (const __attribute__((address_space(1))) unsigned int*)g,
        (__attribute__((address_space(3))) unsigned int*)l, 16, 0, 0);
}

// pack two f32 -> one u32 of 2x bf16 (lo in [15:0], hi in [31:16]), RNE
__device__ __forceinline__ unsigned int cvtpk_bf16(float lo, float hi) {
    unsigned int r;
    asm("v_cvt_pk_bf16_f32 %0, %1, %2" : "=v"(r) : "v"(lo), "v"(hi));
    return r;
}

// ---------------------------------------------------------------------------
// fp32 -> bf16 elementwise, 3 tensors fused via blockIdx.z.
// ---------------------------------------------------------------------------
__global__ __launch_bounds__(256) void cvt_bf16_k(
    const float* __restrict__ x0, const float* __restrict__ x1,
    const float* __restrict__ x2,
    bf16* __restrict__ y0, bf16* __restrict__ y1, bf16* __restrict__ y2)
{
    const float* x = (blockIdx.z == 0) ? x0 : (blockIdx.z == 1) ? x1 : x2;
    bf16*       y = (blockIdx.z == 0) ? y0 : (blockIdx.z == 1) ? y1 : y2;
    const size_t i = ((size_t)blockIdx.x * 256 + threadIdx.x);
    const float4 v = ((const float4*)x)[i];
    union { bf16 h[4]; short4 s; } u;
    u.h[0] = __float2bfloat16(v.x);
    u.h[1] = __float2bfloat16(v.y);
    u.h[2] = __float2bfloat16(v.z);
    u.h[3] = __float2bfloat16(v.w);
    ((short4*)y)[i] = u.s;
}

// ---------------------------------------------------------------------------
// Wt[n][k] = bf16(W[k][n]), 4 weight matrices fused via blockIdx.z.
// ---------------------------------------------------------------------------
__global__ __launch_bounds__(256) void transpose_cvt_k(
    const float* __restrict__ W0, const float* __restrict__ W1,
    const float* __restrict__ W2, const float* __restrict__ W3,
    bf16* __restrict__ T0, bf16* __restrict__ T1,
    bf16* __restrict__ T2, bf16* __restrict__ T3)
{
    const float* W = (blockIdx.z == 0) ? W0 : (blockIdx.z == 1) ? W1
                   : (blockIdx.z == 2) ? W2 : W3;
    bf16*       Wt = (blockIdx.z == 0) ? T0 : (blockIdx.z == 1) ? T1
                   : (blockIdx.z == 2) ? T2 : T3;
    __shared__ float t[32][33];
    const int bx = blockIdx.x << 5, by = blockIdx.y << 5;
    const int tx = threadIdx.x & 31, ty = threadIdx.x >> 5;
#pragma unroll
    for (int i = 0; i < 32; i += 8)
        t[ty + i][tx] = W[(size_t)(by + ty + i) * D_DIM + bx + tx];
    __syncthreads();
#pragma unroll
    for (int i = 0; i < 32; i += 8)
        Wt[(size_t)(bx + ty + i) * D_DIM + by + tx] = __float2bfloat16(t[tx][ty + i]);
}

// ---------------------------------------------------------------------------
// GEMM: C(4096x1024) = A @ Wt^T + bias, then *scale.
// Tile BM=128, BN=64, BK=64; 4 waves 2x2. global_load_lds width-16 staging.
// XCD-locality remap + double-buffered staging (R6) + XOR swizzle (R8,
// verified: bank-conflicts gone, gemm left top-5).
// mode 0: bf16 head-major; mode 2: bf16 [h][hd][row]; mode 1: fp32 row-major.
// ---------------------------------------------------------------------------
struct GemmJob {
    const bf16* A; const bf16* Wt; const float* bias; void* out;
    int mode; float scale;
};

__global__ __launch_bounds__(256) void gemm_k(GemmJob j0, GemmJob j1, GemmJob j2)
{
    const GemmJob j = (blockIdx.z == 0) ? j0 : (blockIdx.z == 1) ? j1 : j2;
    const int K = D_DIM;

    // XCD-locality remap (bijective: nb = gx*gy = 512, divisible by 8).
    const int nx  = gridDim.x;
    const int lin = blockIdx.y * nx + blockIdx.x;
    const int per = (nx * gridDim.y) >> 3;
    const int bmn = (lin & 7) * per + (lin >> 3);
    const int bn = (bmn % nx) << 6;
    const int bm = (bmn / nx) << 7;

    const int tid = threadIdx.x;
    const int w = tid >> 6, lane = tid & 63;
    const int col = lane & 15, g = lane >> 4;
    const int wr = (w >> 1) << 6, wc = (w & 1) << 5;
    const int c7 = col & 7;

    __shared__ bf16 As[2][128 * 64];
    __shared__ bf16 Bs[2][64 * 64];

    f32x4 acc[4][2];
#pragma unroll
    for (int i = 0; i < 4; ++i)
#pragma unroll
        for (int jj = 0; jj < 2; ++jj) acc[i][jj] = (f32x4){0.f, 0.f, 0.f, 0.f};

    auto stage = [&](int buf, int kb) {
#pragma unroll
        for (int e = 0; e < 4; ++e) {
            const int l2 = (e << 8) + tid;
            const int row = l2 >> 3, kc = l2 & 7;
            async_cp16(j.A + (size_t)(bm + row) * K + kb + ((kc ^ (row & 7)) << 3),
                       &As[buf][l2 << 3]);
        }
#pragma unroll
        for (int e = 0; e < 2; ++e) {
            const int l2 = (e << 8) + tid;
            const int row = l2 >> 3, kc = l2 & 7;
            async_cp16(j.Wt + (size_t)(bn + row) * K + kb + ((kc ^ (row & 7)) << 3),
                       &Bs[buf][l2 << 3]);
        }
    };

    stage(0, 0);
    __syncthreads();                       // buf0 ready
    int cur = 0;

    for (int kb = 0; kb < K; kb += 64) {
        if (kb + 64 < K) stage(cur ^ 1, kb + 64);   // prefetch during compute

#pragma unroll
        for (int s = 0; s < 2; ++s) {
            const int gsw = (((s << 2) + g) ^ c7) << 3;   // swizzled granule
            bf16x8v af[4], bfv[2];
#pragma unroll
            for (int i = 0; i < 4; ++i)
                af[i] = *(const bf16x8v*)&As[cur][((wr + (i << 4) + col) << 6) + gsw];
#pragma unroll
            for (int jj = 0; jj < 2; ++jj)
                bfv[jj] = *(const bf16x8v*)&Bs[cur][((wc + (jj << 4) + col) << 6) + gsw];
#pragma unroll
            for (int i = 0; i < 4; ++i)
#pragma unroll
                for (int jj = 0; jj < 2; ++jj)
                    acc[i][jj] = MFMA16(af[i], bfv[jj], acc[i][jj]);
        }

        __syncthreads();                   // drains prefetch + buffer reuse
        cur ^= 1;
    }

#pragma unroll
    for (int i = 0; i < 4; ++i)
#pragma unroll
    for (int jj = 0; jj < 2; ++jj)
#pragma unroll
    for (int reg = 0; reg < 4; ++reg) {
        const int row = bm + wr + (i << 4) + (g << 2) + reg;
        const int cg  = bn + wc + (jj << 4) + col;
        const float vv = (acc[i][jj][reg] + j.bias[cg]) * j.scale;
        if (j.mode == 0)
            ((bf16*)j.out)[(((size_t)(cg >> 6)) * S_LEN + row) * HDIM + (cg & 63)] =
                __float2bfloat16(vv);
        else if (j.mode == 2)
            ((bf16*)j.out)[((size_t)(cg >> 6) * HDIM + (cg & 63)) * S_LEN + row] =
                __float2bfloat16(vv);
        else
            ((float*)j.out)[(size_t)row * D_DIM + cg] = vv;
    }
}

// ---------------------------------------------------------------------------
// Flash attention, zero-shift softmax, swapped QK^T, 2 q-groups/wave, split-k.
// Block = 128 q-rows (4 waves x 32: groups A (+0) and B (+64) share every
// K/V LDS fragment). Qp pre-scaled by log2e/8. SINGLE-buffer K/V (16.4 KB)
// for residency; per-tile: stage -> barrier(DMA drain) -> body -> barrier.
//
// Static job table (mode 1, R6-verified; jid = bid>>4 in [0,48), h = bid&15):
//   jid<16:  qb=31-jid,      tiles [2qb-30, 2qb+2)  split chunk 1, diagonal
//   16..31:  qb=31-(jid-16), tiles [0, 2qb-30)      split chunk 0, no mask
//   32..47:  qb=15-(jid-32), tiles [0, 2qb+2)       unsplit, diagonal
// mode 0: jid in [0,32), qb=31-jid, unsplit (fallback path).
//
// Diagonal peeling (compile-time MODE): main-loop tiles mask-free;
// tile 2qb   = MODE 1 (A diag-masked, B full);
// tile 2qb+1 = MODE 2 (A skipped entirely — P_A == 0 there; B diag-masked).
// Split partials additive (zero-shift): Opart/lpart layout == R4 (verified),
// combine_k does (O0+O1)/(l0+l1) for q-rows 2048..4095.
// ---------------------------------------------------------------------------
__global__ __launch_bounds__(256) void attn_mfma_k(
    const bf16* __restrict__ Qp, const bf16* __restrict__ Kp,
    const bf16* __restrict__ Vt, bf16* __restrict__ ctx,
    float* __restrict__ Opart, float* __restrict__ lpart, int mode)
{
    __shared__ bf16 Ks[4096];        // [t(2b)][G(3b)][c(4b)][8]  16.4 KB total
    __shared__ bf16 Vs[4096];

    const int bid = blockIdx.x;
    const int h   = bid & 15;
    const int jid = bid >> 4;

    int qb, t0, nt, chunk;
    bool dosplit, hdiag;
    if (mode == 1) {
        if (jid < 16)      { qb = 31 - jid;        t0 = 2*qb - 30; nt = 32;        dosplit = true;  chunk = 1; hdiag = true;  }
        else if (jid < 32) { qb = 31 - (jid - 16); t0 = 0;         nt = 2*qb - 30; dosplit = true;  chunk = 0; hdiag = false; }
        else               { qb = 15 - (jid - 32); t0 = 0;         nt = 2*qb + 2;  dosplit = false; chunk = 0; hdiag = true;  }
    } else {
        qb = 31 - jid; t0 = 0; nt = 2*qb + 2; dosplit = false; chunk = 0; hdiag = true;
    }

    const int tid = threadIdx.x, w = tid >> 6, lane = tid & 63;
    const int col = lane & 15, g = lane >> 4;

    const int q0 = qb << 7;
    const bf16* Kh = Kp + (size_t)h * S_LEN * HDIM;
    const bf16* Vh = Vt + (size_t)h * HDIM * S_LEN;

    const int qrowA = q0 + (w << 4) + col;
    const int qrowB = qrowA + 64;
    const size_t qbaseA = ((size_t)h * S_LEN + qrowA) * HDIM + (g << 3);
    const size_t qbaseB = qbaseA + (size_t)64 * HDIM;
    const bf16x8v qfA0 = *(const bf16x8v*)(Qp + qbaseA);
    const bf16x8v qfA1 = *(const bf16x8v*)(Qp + qbaseA + 32);
    const bf16x8v qfB0 = *(const bf16x8v*)(Qp + qbaseB);
    const bf16x8v qfB1 = *(const bf16x8v*)(Qp + qbaseB + 32);

    float plA = 0.f, plB = 0.f;
    f32x4 accA[4], accB[4];
#pragma unroll
    for (int t = 0; t < 4; ++t) {
        accA[t] = (f32x4){0.f, 0.f, 0.f, 0.f};
        accB[t] = (f32x4){0.f, 0.f, 0.f, 0.f};
    }

    auto stage = [&](int kb) {
        const int kk0 = kb << 6;
#pragma unroll
        for (int e = 0; e < 2; ++e) {
            const int lin = (e << 8) + tid;            // granule 0..511
            const int t = lin >> 7, G = (lin >> 4) & 7, c = lin & 15;
            async_cp16(Kh + (size_t)(kk0 + (t << 4) + c) * HDIM + (G << 3),
                       &Ks[lin << 3]);
            async_cp16(Vh + (size_t)((t << 4) + c) * S_LEN + kk0 + (G << 3),
                       &Vs[lin << 3]);
        }
    };

    // MODE 0: no masks.  MODE 1: A diag-masked, B full.  MODE 2: A skipped,
    // B diag-masked.
    auto body = [&](auto mtag, int kb) {
        constexpr int MODE = decltype(mtag)::value;
        const int kk0 = kb << 6;

        f32x4 saA[4], saB[4];
#pragma unroll
        for (int t = 0; t < 4; ++t) {
            saA[t] = (f32x4){0.f, 0.f, 0.f, 0.f};
            saB[t] = (f32x4){0.f, 0.f, 0.f, 0.f};
        }
        __builtin_amdgcn_s_setprio(1);
#pragma unroll
        for (int t = 0; t < 4; ++t) {
            const bf16x8v kf0 = *(const bf16x8v*)&Ks[((t << 7) + (g << 4) + col) << 3];
            const bf16x8v kf1 = *(const bf16x8v*)&Ks[((t << 7) + 64 + (g << 4) + col) << 3];
            if (MODE != 2) {
                saA[t] = MFMA16(kf0, qfA0, saA[t]);
                saA[t] = MFMA16(kf1, qfA1, saA[t]);
            }
            saB[t] = MFMA16(kf0, qfB0, saB[t]);
            saB[t] = MFMA16(kf1, qfB1, saB[t]);
        }
        __builtin_amdgcn_s_setprio(0);

#pragma unroll
        for (int t = 0; t < 4; ++t) {
#pragma unroll
            for (int reg = 0; reg < 4; ++reg) {
                const int kidx = kk0 + (t << 4) + (g << 2) + reg;
                if (MODE != 2) {
                    float pA;
                    if (MODE == 1 && kidx > qrowA) pA = 0.f;
                    else                           pA = EXP2F(saA[t][reg]);
                    plA += pA; saA[t][reg] = pA;
                }
                float pB;
                if (MODE == 2 && kidx > qrowB) pB = 0.f;
                else                           pB = EXP2F(saB[t][reg]);
                plB += pB; saB[t][reg] = pB;
            }
        }

        union { unsigned int wd[4]; bf16x8v v; } pA0, pA1, pB0, pB1;
        if (MODE != 2) {
            unsigned int c0[4], c1[4];
#pragma unroll
            for (int t = 0; t < 4; ++t) {
                c0[t] = cvtpk_bf16(saA[t][0], saA[t][1]);
                c1[t] = cvtpk_bf16(saA[t][2], saA[t][3]);
            }
            u32x2 r0 = __builtin_amdgcn_permlane32_swap(c0[0], c0[1], false, false);
            u32x2 r1 = __builtin_amdgcn_permlane32_swap(c1[0], c1[1], false, false);
            u32x2 s0 = __builtin_amdgcn_permlane16_swap(r0[0], r0[1], false, false);
            u32x2 s1 = __builtin_amdgcn_permlane16_swap(r1[0], r1[1], false, false);
            pA0.wd[0] = s0[0]; pA0.wd[1] = s1[0]; pA0.wd[2] = s0[1]; pA0.wd[3] = s1[1];
            r0 = __builtin_amdgcn_permlane32_swap(c0[2], c0[3], false, false);
            r1 = __builtin_amdgcn_permlane32_swap(c1[2], c1[3], false, false);
            s0 = __builtin_amdgcn_permlane16_swap(r0[0], r0[1], false, false);
            s1 = __builtin_amdgcn_permlane16_swap(r1[0], r1[1], false, false);
            pA1.wd[0] = s0[0]; pA1.wd[1] = s1[0]; pA1.wd[2] = s0[1]; pA1.wd[3] = s1[1];
        }
        {
            unsigned int c0[4], c1[4];
#pragma unroll
            for (int t = 0; t < 4; ++t) {
                c0[t] = cvtpk_bf16(saB[t][0], saB[t][1]);
                c1[t] = cvtpk_bf16(saB[t][2], saB[t][3]);
            }
            u32x2 r0 = __builtin_amdgcn_permlane32_swap(c0[0], c0[1], false, false);
            u32x2 r1 = __builtin_amdgcn_permlane32_swap(c1[0], c1[1], false, false);
            u32x2 s0 = __builtin_amdgcn_permlane16_swap(r0[0], r0[1], false, false);
            u32x2 s1 = __builtin_amdgcn_permlane16_swap(r1[0], r1[1], false, false);
            pB0.wd[0] = s0[0]; pB0.wd[1] = s1[0]; pB0.wd[2] = s0[1]; pB0.wd[3] = s1[1];
            r0 = __builtin_amdgcn_permlane32_swap(c0[2], c0[3], false, false);
            r1 = __builtin_amdgcn_permlane32_swap(c1[2], c1[3], false, false);
            s0 = __builtin_amdgcn_permlane16_swap(r0[0], r0[1], false, false);
            s1 = __builtin_amdgcn_permlane16_swap(r1[0], r1[1], false, false);
            pB1.wd[0] = s0[0]; pB1.wd[1] = s1[0]; pB1.wd[2] = s0[1]; pB1.wd[3] = s1[1];
        }

        __builtin_amdgcn_s_setprio(1);
#pragma unroll
        for (int t = 0; t < 4; ++t) {
            const bf16x8v vf0 = *(const bf16x8v*)&Vs[((t << 7) + (g << 4) + col) << 3];
            const bf16x8v vf1 = *(const bf16x8v*)&Vs[((t << 7) + 64 + (g << 4) + col) << 3];
            if (MODE != 2) {
                accA[t] = MFMA16(vf0, pA0.v, accA[t]);
                accA[t] = MFMA16(vf1, pA1.v, accA[t]);
            }
            accB[t] = MFMA16(vf0, pB0.v, accB[t]);
            accB[t] = MFMA16(vf1, pB1.v, accB[t]);
        }
        __builtin_amdgcn_s_setprio(0);
    };

    int kb = t0;
    const int nmain = hdiag ? nt - 2 : nt;
    for (int i = 0; i < nmain; ++i, ++kb) {
        stage(kb);
        __syncthreads();                   // DMA drained: tile ready
        body(IC<0>{}, kb);
        __syncthreads();                   // all reads done before overwrite
    }
    if (hdiag) {
        stage(kb);
        __syncthreads();
        body(IC<1>{}, kb);                 // tile 2qb: A diag, B full
        __syncthreads();
        ++kb;
        stage(kb);
        __syncthreads();
        body(IC<2>{}, kb);                 // tile 2qb+1: A skipped, B diag
    }

    // row-sums: reduce across the 4 g-groups (lane bits 4,5); q = col
    float lA = plA, lB = plB;
    lA += __shfl_xor(lA, 16); lA += __shfl_xor(lA, 32);
    lB += __shfl_xor(lB, 16); lB += __shfl_xor(lB, 32);

    if (!dosplit) {
        const float invA = 1.f / lA;
        const float invB = 1.f / lB;
#pragma unroll
        for (int t = 0; t < 4; ++t) {
            union { bf16 hh[4]; short4 s4; } uA, uB;
#pragma unroll
            for (int reg = 0; reg < 4; ++reg) {
                uA.hh[reg] = __float2bfloat16(accA[t][reg] * invA);
                uB.hh[reg] = __float2bfloat16(accB[t][reg] * invB);
            }
            *(short4*)&ctx[(size_t)qrowA * D_DIM + h * HDIM + (t << 4) + (g << 2)] = uA.s4;
            *(short4*)&ctx[(size_t)qrowB * D_DIM + h * HDIM + (t << 4) + (g << 2)] = uB.s4;
        }
    } else {
        // unnormalized f32 partials; additive across chunks (zero-shift)
        const int srowA = ((qb - 16) << 7) + (w << 4) + col;      // 0..2047
        const int srowB = srowA + 64;
        float* OpA = Opart + (((size_t)chunk * NHEAD + h) * 2048 + srowA) * HDIM;
        float* OpB = Opart + (((size_t)chunk * NHEAD + h) * 2048 + srowB) * HDIM;
#pragma unroll
        for (int t = 0; t < 4; ++t) {
            *(f32x4*)&OpA[(t << 4) + (g << 2)] = accA[t];
            *(f32x4*)&OpB[(t << 4) + (g << 2)] = accB[t];
        }
        if (g == 0) {
            lpart[((size_t)chunk * NHEAD + h) * 2048 + srowA] = lA;
            lpart[((size_t)chunk * NHEAD + h) * 2048 + srowB] = lB;
        }
    }
}

// ---------------------------------------------------------------------------
// Combine split-k partials: ctx[2048+srow] = (O0+O1)/(l0+l1).
// 32768 (h,srow) rows x 64 d; 16 threads/row (4 d each), 16 rows/block.
// ---------------------------------------------------------------------------
__global__ __launch_bounds__(256) void combine_k(
    const float* __restrict__ Opart, const float* __restrict__ lpart,
    bf16* __restrict__ ctx)
{
    const int tid = threadIdx.x;
    const int row = (blockIdx.x << 4) + (tid >> 4);   // 0..32767 = h*2048+srow
    const int d4  = (tid & 15) << 2;
    const int h   = row >> 11;
    const int srow = row & 2047;
    const float4 a = *(const float4*)&Opart[(size_t)row * HDIM + d4];
    const float4 b = *(const float4*)&Opart[(size_t)(32768 + row) * HDIM + d4];
    const float inv = 1.f / (lpart[row] + lpart[32768 + row]);
    union { bf16 hh[4]; short4 s4; } u;
    u.hh[0] = __float2bfloat16((a.x + b.x) * inv);
    u.hh[1] = __float2bfloat16((a.y + b.y) * inv);
    u.hh[2] = __float2bfloat16((a.z + b.z) * inv);
    u.hh[3] = __float2bfloat16((a.w + b.w) * inv);
    const int qrow = 2048 + srow;
    *(short4*)&ctx[(size_t)qrow * D_DIM + h * HDIM + d4] = u.s4;
}

// ---------------------------------------------------------------------------
extern "C" void kernel_launch(void* const* d_in, const int* in_sizes, int n_in,
                              void* d_out, int out_size, void* d_ws, size_t ws_size,
                              hipStream_t stream)
{
    const float* q  = (const float*)d_in[0];
    const float* k  = (const float*)d_in[1];
    const float* v  = (const float*)d_in[2];
    // d_in[3] = causal mask, implemented analytically
    const float* Wq = (const float*)d_in[4];
    const float* bq = (const float*)d_in[5];
    const float* Wk = (const float*)d_in[6];
    const float* bk = (const float*)d_in[7];
    const float* Wv = (const float*)d_in[8];
    const float* bv = (const float*)d_in[9];
    const float* Wo = (const float*)d_in[10];
    const float* bo = (const float*)d_in[11];

    const size_t PE  = (size_t)S_LEN * D_DIM;
    const size_t WTE = (size_t)D_DIM * D_DIM;

    const dim3 tg(32, 32, 4);
    const dim3 gg(D_DIM / 64, S_LEN / 128, 1);
    const dim3 gg3(D_DIM / 64, S_LEN / 128, 3);
    const dim3 cg((unsigned)(PE / 1024), 1, 3);

    if (ws_size >= (size_t)64 * 1024 * 1024) {
        // ---- fused-QKV path (56 MB + partials) ----
        bf16* Qb = (bf16*)d_ws;
        bf16* Kb = Qb + PE;
        bf16* Vb = Kb + PE;
        bf16* Qp = Vb + PE;
        bf16* Kp = Qp + PE;
        bf16* Vt = Kp + PE;
        bf16* Wtq = Vt + PE;
        bf16* Wtk = Wtq + WTE;
        bf16* Wtv = Wtk + WTE;
        bf16* Wto = Wtv + WTE;
        bf16* ctx = Qb;
        // Kb/Vb are dead after the projection GEMMs -> reuse for partials.
        float* Opart = (float*)Kb;                 // 2*16*2048*64 f32 = 16 MB
        float* lpart = (float*)(Wto + WTE);        // 2*16*2048 f32 = 256 KB

        transpose_cvt_k<<<tg, 256, 0, stream>>>(Wq, Wk, Wv, Wo, Wtq, Wtk, Wtv, Wto);
        cvt_bf16_k<<<cg, 256, 0, stream>>>(q, k, v, Qb, Kb, Vb);

        GemmJob jqj{Qb, Wtq, bq, Qp, 0, QSCALE};
        GemmJob jkj{Kb, Wtk, bk, Kp, 0, 1.0f};
        GemmJob jvj{Vb, Wtv, bv, Vt, 2, 1.0f};
        gemm_k<<<gg3, 256, 0, stream>>>(jqj, jkj, jvj);

        attn_mfma_k<<<dim3(768), 256, 0, stream>>>(Qp, Kp, Vt, ctx, Opart, lpart, 1);
        combine_k<<<dim3(2048), 256, 0, stream>>>(Opart, lpart, ctx);

        GemmJob joj{ctx, Wto, bo, d_out, 1, 1.0f};
        gemm_k<<<gg, 256, 0, stream>>>(joj, joj, joj);
    } else {
        // ---- sequential path (40 MB, no split-k workspace) ----
        bf16* X  = (bf16*)d_ws;
        bf16* Qp = X + PE;
        bf16* Kp = Qp + PE;
        bf16* Vt = Kp + PE;
        bf16* Wtq = Vt + PE;
        bf16* Wtk = Wtq + WTE;
        bf16* Wtv = Wtk + WTE;
        bf16* Wto = Wtv + WTE;

        transpose_cvt_k<<<tg, 256, 0, stream>>>(Wq, Wk, Wv, Wo, Wtq, Wtk, Wtv, Wto);

        const dim3 cg1((unsigned)(PE / 1024), 1, 1);
        cvt_bf16_k<<<cg1, 256, 0, stream>>>(q, q, q, X, X, X);
        GemmJob jqj{X, Wtq, bq, Qp, 0, QSCALE};
        gemm_k<<<gg, 256, 0, stream>>>(jqj, jqj, jqj);
        cvt_bf16_k<<<cg1, 256, 0, stream>>>(k, k, k, X, X, X);
        GemmJob jkj{X, Wtk, bk, Kp, 0, 1.0f};
        gemm_k<<<gg, 256, 0, stream>>>(jkj, jkj, jkj);
        cvt_bf16_k<<<cg1, 256, 0, stream>>>(v, v, v, X, X, X);
        GemmJob jvj{X, Wtv, bv, Vt, 2, 1.0f};
        gemm_k<<<gg, 256, 0, stream>>>(jvj, jvj, jvj);

        attn_mfma_k<<<dim3(512), 256, 0, stream>>>(Qp, Kp, Vt, X, nullptr, nullptr, 0);

        GemmJob joj{X, Wto, bo, d_out, 1, 1.0f};
        gemm_k<<<gg, 256, 0, stream>>>(joj, joj, joj);
    }
}